// Round 4
// baseline (345.496 us; speedup 1.0000x reference)
//
#include <hip/hip_runtime.h>
#include <hip/hip_bf16.h>
#include <cstdint>

// B=1, S=4096, HID=2048, NH=16, NKV=4, HD=128, BLK=128, LOCAL=4, GLOB=4, STRIDE=8
#define NEGV   (-1000000000.0f)
#define SCALE  0.08838834764831845f            // 128^-0.5
#define LOG2E  1.4426950408889634f
#define QSC    (SCALE * LOG2E)                 // folded into Q at qkv epilogue
#define NEGL2  (NEGV * LOG2E)                  // mask bias in exp2 domain

typedef __bf16 bf16x8 __attribute__((ext_vector_type(8)));
typedef float  f32x4  __attribute__((ext_vector_type(4)));
typedef unsigned short u16;
typedef unsigned int   u32;

#define MFMA16(a, b, c) __builtin_amdgcn_mfma_f32_16x16x32_bf16((a), (b), (c), 0, 0, 0)

// ---- workspace layout (u16 units). AOp aliases Xp (X dead after qkv GEMM).
#define WS_XP    ((size_t)0)          // X frag-order, 16 MiB
#define WS_AOP   ((size_t)0)          // attn out frag-order (alias)
#define WS_WQP   ((size_t)8388608)    // Wq^T frag-order, 8 MiB
#define WS_WKP   ((size_t)12582912)   // Wk^T frag-order, 2 MiB
#define WS_WVP   ((size_t)13631488)   // Wv^T frag-order, 2 MiB
#define WS_WOP   ((size_t)14680064)   // Wo^T frag-order, 8 MiB
#define WS_QF    ((size_t)18874368)   // Q attn-A-frag order [h][4096x128], 16 MiB
#define WS_KF    ((size_t)27262976)   // K attn-B-frag order [kvh][4096x128], 4 MiB
#define WS_VF    ((size_t)29360128)   // V attn-PV-frag order[kvh][128x4096], 4 MiB

__device__ __forceinline__ u16 f2bf(float f) {
  union { float f; u32 u; } v; v.f = f;
  u32 u = v.u;
  u += 0x7FFFu + ((u >> 16) & 1u);   // RNE
  return (u16)(u >> 16);
}

__device__ __forceinline__ void gl_lds16(const u16* g, u16* l) {
  __builtin_amdgcn_global_load_lds((const __attribute__((address_space(1))) u32*)g,
                                   (__attribute__((address_space(3))) u32*)l,
                                   16, 0, 0);
}

// fragment-order u16 offset within a 128(row) x 32(k) tile
__device__ __forceinline__ int fragoff(int row, int k) {
  return ((row >> 4) * 64 + ((k >> 3) & 3) * 16 + (row & 15)) * 8 + (k & 7);
}

// ============================================================================
// Kernel 0: one-time fp32 -> bf16 conversion into fragment-order layouts.
// ============================================================================
__global__ __launch_bounds__(256, 4)
void convert_kernel(const float* __restrict__ X,
                    const float* __restrict__ Wq,
                    const float* __restrict__ Wk,
                    const float* __restrict__ Wv,
                    const float* __restrict__ Wo,
                    u16* __restrict__ ws)
{
  const int t = blockIdx.x;
  const int tid = threadIdx.x;
  const float* src; u16* dst; int tt, ldn; bool amode = false;
  if (t < 2048)      { src = X;  dst = ws + WS_XP;  tt = t;        ldn = 2048; amode = true; }
  else if (t < 3072) { src = Wq; dst = ws + WS_WQP; tt = t - 2048; ldn = 2048; }
  else if (t < 3328) { src = Wk; dst = ws + WS_WKP; tt = t - 3072; ldn = 512;  }
  else if (t < 3584) { src = Wv; dst = ws + WS_WVP; tt = t - 3328; ldn = 512;  }
  else               { src = Wo; dst = ws + WS_WOP; tt = t - 3584; ldn = 2048; }
  const int rb = tt >> 6, kb = tt & 63;

  if (amode) {
    #pragma unroll
    for (int p = 0; p < 2; ++p) {
      const int c = tid + 256 * p;
      const int row = (c >> 6) * 16 + (c & 15);
      const int k0  = ((c >> 4) & 3) * 8;
      union { u16 h[8]; uint4 v; } pk;
      const float* s0 = src + (size_t)(rb * 128 + row) * 2048 + kb * 32 + k0;
      const float4 a0 = *reinterpret_cast<const float4*>(s0);
      const float4 a1 = *reinterpret_cast<const float4*>(s0 + 4);
      pk.h[0] = f2bf(a0.x); pk.h[1] = f2bf(a0.y); pk.h[2] = f2bf(a0.z); pk.h[3] = f2bf(a0.w);
      pk.h[4] = f2bf(a1.x); pk.h[5] = f2bf(a1.y); pk.h[6] = f2bf(a1.z); pk.h[7] = f2bf(a1.w);
      *reinterpret_cast<uint4*>(dst + (size_t)tt * 4096 + c * 8) = pk.v;
    }
  } else {
    __shared__ u16 Ls[32][136];   // [k][n], +8 pad
    #pragma unroll
    for (int i = 0; i < 4; ++i) {
      const int c = tid + 256 * i;            // 0..1023
      const int k = c >> 5, n4 = c & 31;
      const float4 wv = *reinterpret_cast<const float4*>(
          src + (size_t)(kb * 32 + k) * ldn + rb * 128 + n4 * 4);
      u16* d = &Ls[k][n4 * 4];
      d[0] = f2bf(wv.x); d[1] = f2bf(wv.y); d[2] = f2bf(wv.z); d[3] = f2bf(wv.w);
    }
    __syncthreads();
    #pragma unroll
    for (int p = 0; p < 2; ++p) {
      const int c = tid + 256 * p;
      const int row = (c >> 6) * 16 + (c & 15);
      const int k0  = ((c >> 4) & 3) * 8;
      union { u16 h[8]; uint4 v; } pk;
      #pragma unroll
      for (int j = 0; j < 8; ++j) pk.h[j] = Ls[k0 + j][row];
      *reinterpret_cast<uint4*>(dst + (size_t)tt * 4096 + c * 8) = pk.v;
    }
  }
}

// ---- shared GEMM main loop: 128x128 tile, BK=32, K=2048, frag-order inputs.
__device__ __forceinline__ void gemm_core(const u16* __restrict__ pa,
                                          const u16* __restrict__ pb,
                                          u16* As, u16* Bs,
                                          int tid, int wave, int lane,
                                          f32x4 acc[2][8])
{
  for (int it = 0; it < 64; ++it) {
    __syncthreads();
    gl_lds16(pa + tid * 8,         As + tid * 8);
    gl_lds16(pa + (tid + 256) * 8, As + (tid + 256) * 8);
    gl_lds16(pb + tid * 8,         Bs + tid * 8);
    gl_lds16(pb + (tid + 256) * 8, Bs + (tid + 256) * 8);
    pa += 4096; pb += 4096;
    __syncthreads();
    bf16x8 af0 = *reinterpret_cast<const bf16x8*>(As + (wave * 2 + 0) * 512 + lane * 8);
    bf16x8 af1 = *reinterpret_cast<const bf16x8*>(As + (wave * 2 + 1) * 512 + lane * 8);
    #pragma unroll
    for (int nt = 0; nt < 8; ++nt) {
      const bf16x8 bfr = *reinterpret_cast<const bf16x8*>(Bs + nt * 512 + lane * 8);
      acc[0][nt] = MFMA16(af0, bfr, acc[0][nt]);
      acc[1][nt] = MFMA16(af1, bfr, acc[1][nt]);
    }
  }
}

// ============================================================================
// Kernel 1: QKV GEMM + fused RoPE -> attention frag-order outputs.
// Q is pre-scaled by SCALE*log2(e) so attention softmax runs in exp2 domain.
// ============================================================================
__global__ __launch_bounds__(256, 2)
void qkv_kernel(const float* __restrict__ cosp,
                const float* __restrict__ sinp,
                u16* __restrict__ ws)
{
  const int mb = blockIdx.x, bn = blockIdx.y;
  const int tid = threadIdx.x;
  const int wave = tid >> 6, lane = tid & 63;
  const int lq = lane >> 4, l16 = lane & 15;

  const u16* Ab = ws + WS_XP + (size_t)mb * 64 * 4096;
  const u16* Bb; int seg, hh;
  if (bn < 16)      { Bb = ws + WS_WQP + (size_t)bn * 64 * 4096;        seg = 0; hh = bn; }
  else if (bn < 20) { Bb = ws + WS_WKP + (size_t)(bn - 16) * 64 * 4096; seg = 1; hh = bn - 16; }
  else              { Bb = ws + WS_WVP + (size_t)(bn - 20) * 64 * 4096; seg = 2; hh = bn - 20; }

  __shared__ __align__(16) u16 As[4096];
  __shared__ __align__(16) u16 Bs[4096];

  f32x4 acc[2][8];
  #pragma unroll
  for (int i = 0; i < 2; ++i)
    #pragma unroll
    for (int j = 0; j < 8; ++j)
      #pragma unroll
      for (int r = 0; r < 4; ++r) acc[i][j][r] = 0.0f;

  gemm_core(Ab, Bb, As, Bs, tid, wave, lane, acc);

  const int m0 = mb * 128;
  if (seg == 2) {          // V -> PV B-frag order (rows=d, k=t)
    u16* V = ws + WS_VF + (size_t)hh * 524288;
    #pragma unroll
    for (int mt = 0; mt < 2; ++mt)
      #pragma unroll
      for (int nt = 0; nt < 8; ++nt) {
        const int d = nt * 16 + l16;
        #pragma unroll
        for (int r = 0; r < 4; ++r) {
          const int s = m0 + wave * 32 + mt * 16 + lq * 4 + r;
          V[(s >> 5) * 4096 + fragoff(d, s & 31)] = f2bf(acc[mt][nt][r]);
        }
      }
  } else {                 // Q/K + RoPE (cos[d+64]==cos[d]); Q also *QSC
    u16* D = ws + ((seg == 0) ? WS_QF : WS_KF) + (size_t)hh * 524288;
    const float qs = (seg == 0) ? QSC : 1.0f;
    #pragma unroll
    for (int mt = 0; mt < 2; ++mt)
      #pragma unroll
      for (int r = 0; r < 4; ++r) {
        const int s = m0 + wave * 32 + mt * 16 + lq * 4 + r;
        const int sl = s & 127;
        u16* Dt = D + (size_t)(s >> 7) * 16384;
        #pragma unroll
        for (int nt = 0; nt < 4; ++nt) {
          const int d1 = nt * 16 + l16, d2 = d1 + 64;
          const float c  = cosp[s * 128 + d1];
          const float sn = sinp[s * 128 + d1];
          const float v1 = acc[mt][nt][r], v2 = acc[mt][nt + 4][r];
          Dt[(d1 >> 5) * 4096 + fragoff(sl, d1 & 31)] = f2bf((v1 * c - v2 * sn) * qs);
          Dt[(d2 >> 5) * 4096 + fragoff(sl, d2 & 31)] = f2bf((v2 * c + v1 * sn) * qs);
        }
      }
  }
}

// ============================================================================
// Kernel 2: block-sparse attention. 512 thr = 8 waves x 16 q-rows.
// 96 KB dynamic LDS (1 block/CU): K 32K | V 32K | P 32K. Grid 512 = 2 rounds
// per CU -> skip-rebalancing works; heavy-n blocks dispatched first (LPT).
// K/V for the next valid kb prefetched into REGISTERS during compute.
// ============================================================================
__global__ __launch_bounds__(512, 2)
void attn_kernel(const float* __restrict__ amask, u16* __restrict__ ws)
{
  extern __shared__ u16 smem[];
  u16* bufK = smem;            // 16384 u16
  u16* bufV = smem + 16384;    // 16384 u16
  const int bx = blockIdx.x;
  const int n = 31 - (bx >> 4);          // heavy blocks first
  const int h = bx & 15;
  const int kvh = h >> 2;
  const int tid = threadIdx.x;
  const int wave = tid >> 6, lane = tid & 63;
  const int lq = lane >> 4, l16 = lane & 15;

  const u16* Kfb = ws + WS_KF + (size_t)kvh * 524288;
  const u16* Vfb = ws + WS_VF + (size_t)kvh * 524288;
  u16* AOp = ws + WS_AOP;
  u16* Pw = smem + 32768 + wave * 2048;  // wave-private 16x128 P region

  const u16* Qb = ws + WS_QF + (size_t)h * 524288 + (size_t)n * 16384;
  bf16x8 qf[4];
  #pragma unroll
  for (int kk = 0; kk < 4; ++kk)
    qf[kk] = *reinterpret_cast<const bf16x8*>(Qb + (size_t)kk * 4096 + (wave * 64 + lane) * 8);

  f32x4 O[8];
  #pragma unroll
  for (int j = 0; j < 8; ++j)
    #pragma unroll
    for (int r = 0; r < 4; ++r) O[j][r] = 0.0f;
  float mrow[4], lrow[4];
  #pragma unroll
  for (int r = 0; r < 4; ++r) { mrow[r] = -3.0e38f; lrow[r] = 0.0f; }

  // closed-form valid-kb list (reference semantics, verified R1-R3):
  // locals ascending (last one = diagonal, intra-masked), then g0=0, then
  // valid strided globals ascending.
  const int L = (n < 3 ? n : 3) + 1;
  const int G = (n >= 25) ? 3 : (n >= 17) ? 2 : (n >= 9) ? 1 : 0;
  const int nv = L + 1 + G;
  #define KBOF(i) ((i) < L ? n - L + 1 + (i) : ((i) == L ? 0 : n - 8 * (G - ((i) - L - 1))))

  // prologue: prefetch kb 0 into regs
  uint4 pk[4], pv[4]; float biasN[8];
  {
    const int b0 = KBOF(0);
    const u16* Kb = Kfb + (size_t)b0 * 16384;
    const u16* Vb = Vfb + (size_t)b0 * 16384;
    #pragma unroll
    for (int p = 0; p < 4; ++p) {
      pk[p] = *reinterpret_cast<const uint4*>(Kb + (tid + 512 * p) * 8);
      pv[p] = *reinterpret_cast<const uint4*>(Vb + (tid + 512 * p) * 8);
    }
    #pragma unroll
    for (int nt = 0; nt < 8; ++nt)
      biasN[nt] = (1.0f - amask[b0 * 128 + nt * 16 + l16]) * NEGL2;
  }

  #pragma unroll
  for (int i = 0; i < 8; ++i) {
    if (i >= nv) break;
    const bool intra = (i == L - 1);

    __syncthreads();   // all waves done reading bufK/bufV from prev iter
    #pragma unroll
    for (int p = 0; p < 4; ++p) {
      *reinterpret_cast<uint4*>(bufK + (tid + 512 * p) * 8) = pk[p];
      *reinterpret_cast<uint4*>(bufV + (tid + 512 * p) * 8) = pv[p];
    }
    float biasC[8];
    #pragma unroll
    for (int nt = 0; nt < 8; ++nt) biasC[nt] = biasN[nt];
    if (i + 1 < nv) {                  // register-prefetch next valid kb
      const int nb = KBOF(i + 1);
      const u16* Kb = Kfb + (size_t)nb * 16384;
      const u16* Vb = Vfb + (size_t)nb * 16384;
      #pragma unroll
      for (int p = 0; p < 4; ++p) {
        pk[p] = *reinterpret_cast<const uint4*>(Kb + (tid + 512 * p) * 8);
        pv[p] = *reinterpret_cast<const uint4*>(Vb + (tid + 512 * p) * 8);
      }
      #pragma unroll
      for (int nt = 0; nt < 8; ++nt)
        biasN[nt] = (1.0f - amask[nb * 128 + nt * 16 + l16]) * NEGL2;
    }
    __syncthreads();   // staged tile visible

    // S = Q K^T (Q pre-scaled; scores in exp2 domain)
    f32x4 sacc[8];
    #pragma unroll
    for (int j = 0; j < 8; ++j)
      #pragma unroll
      for (int r = 0; r < 4; ++r) sacc[j][r] = 0.0f;
    #pragma unroll
    for (int kk = 0; kk < 4; ++kk)
      #pragma unroll
      for (int nt = 0; nt < 8; ++nt) {
        const bf16x8 bfr = *reinterpret_cast<const bf16x8*>(
            bufK + ((kk * 8 + nt) * 64 + lane) * 8);
        sacc[nt] = MFMA16(qf[kk], bfr, sacc[nt]);
      }

    // online softmax (exp2 domain) + P write into wave-private region
    #pragma unroll
    for (int r = 0; r < 4; ++r) {
      const int tq = wave * 16 + lq * 4 + r;
      float sv[8];
      float rmax = -3.0e38f;
      #pragma unroll
      for (int nt = 0; nt < 8; ++nt) {
        float s = sacc[nt][r] + biasC[nt];
        const int tk = nt * 16 + l16;
        if (intra && tk > tq) s += NEGL2;
        sv[nt] = s;
        rmax = fmaxf(rmax, s);
      }
      #pragma unroll
      for (int off = 1; off < 16; off <<= 1)
        rmax = fmaxf(rmax, __shfl_xor(rmax, off, 64));
      const float mold = mrow[r];
      const float mnew = fmaxf(mold, rmax);
      const float alpha = exp2f(mold - mnew);
      float rsum = 0.0f;
      u16 pb[8];
      #pragma unroll
      for (int nt = 0; nt < 8; ++nt) {
        const float pe = exp2f(sv[nt] - mnew);
        rsum += pe;
        pb[nt] = f2bf(pe);
      }
      #pragma unroll
      for (int off = 1; off < 16; off <<= 1)
        rsum += __shfl_xor(rsum, off, 64);
      lrow[r] = lrow[r] * alpha + rsum;
      mrow[r] = mnew;
      #pragma unroll
      for (int nt = 0; nt < 8; ++nt) O[nt][r] *= alpha;
      // scatter P into A-frag order: elem(m=lq*4+r, k=nt*16+l16)
      #pragma unroll
      for (int nt = 0; nt < 8; ++nt)
        Pw[(nt >> 1) * 512 + ((((nt & 1) * 2 + (l16 >> 3)) * 16) + lq * 4 + r) * 8 + (l16 & 7)] = pb[nt];
    }

    // O += P @ V (own-wave P region; no barrier needed)
    #pragma unroll
    for (int kk = 0; kk < 4; ++kk) {
      const bf16x8 pf = *reinterpret_cast<const bf16x8*>(Pw + kk * 512 + lane * 8);
      #pragma unroll
      for (int nt = 0; nt < 8; ++nt) {
        const bf16x8 vfr = *reinterpret_cast<const bf16x8*>(
            bufV + ((kk * 8 + nt) * 64 + lane) * 8);
        O[nt] = MFMA16(pf, vfr, O[nt]);
      }
    }
  }
  #undef KBOF

  // finalize: write AO in outproj A-frag order
  #pragma unroll
  for (int r = 0; r < 4; ++r) {
    const float inv = 1.0f / lrow[r];
    const int s = n * 128 + wave * 16 + lq * 4 + r;
    #pragma unroll
    for (int nt = 0; nt < 8; ++nt) {
      const int kcol = h * 128 + nt * 16 + l16;
      AOp[((size_t)(s >> 7) * 64 + (kcol >> 5)) * 4096 + fragoff(s & 127, kcol & 31)] =
          f2bf(O[nt][r] * inv);
    }
  }
}

// ============================================================================
// Kernel 3: output projection. AOp fragorder @ Wop fragorder -> Out fp32.
// ============================================================================
__global__ __launch_bounds__(256, 2)
void outproj_kernel(const u16* __restrict__ ws, float* __restrict__ Out)
{
  const int mb = blockIdx.x, bn = blockIdx.y;
  const int tid = threadIdx.x;
  const int wave = tid >> 6, lane = tid & 63;
  const int lq = lane >> 4, l16 = lane & 15;

  const u16* Ab = ws + WS_AOP + (size_t)mb * 64 * 4096;
  const u16* Bb = ws + WS_WOP + (size_t)bn * 64 * 4096;

  __shared__ __align__(16) u16 As[4096];
  __shared__ __align__(16) u16 Bs[4096];

  f32x4 acc[2][8];
  #pragma unroll
  for (int i = 0; i < 2; ++i)
    #pragma unroll
    for (int j = 0; j < 8; ++j)
      #pragma unroll
      for (int r = 0; r < 4; ++r) acc[i][j][r] = 0.0f;

  gemm_core(Ab, Bb, (u16*)As, (u16*)Bs, tid, wave, lane, acc);

  #pragma unroll
  for (int mt = 0; mt < 2; ++mt)
    #pragma unroll
    for (int nt = 0; nt < 8; ++nt) {
      const int ccol = bn * 128 + nt * 16 + l16;
      #pragma unroll
      for (int r = 0; r < 4; ++r) {
        const int s = mb * 128 + wave * 32 + mt * 16 + lq * 4 + r;
        Out[(size_t)s * 2048 + ccol] = acc[mt][nt][r];
      }
    }
}

// ============================================================================
extern "C" void kernel_launch(void* const* d_in, const int* in_sizes, int n_in,
                              void* d_out, int out_size, void* d_ws, size_t ws_size,
                              hipStream_t stream) {
  const float* X     = (const float*)d_in[0];
  const float* amask = (const float*)d_in[1];
  const float* cosp  = (const float*)d_in[2];
  const float* sinp  = (const float*)d_in[3];
  const float* Wq    = (const float*)d_in[4];
  const float* Wk    = (const float*)d_in[5];
  const float* Wv    = (const float*)d_in[6];
  const float* Wo    = (const float*)d_in[7];
  float* Out = (float*)d_out;
  u16* ws = (u16*)d_ws;

  static int lds_set = 0;
  (void)hipFuncSetAttribute((const void*)attn_kernel,
                            hipFuncAttributeMaxDynamicSharedMemorySize, 98304);
  (void)lds_set;

  hipLaunchKernelGGL(convert_kernel, dim3(4608), dim3(256), 0, stream,
                     X, Wq, Wk, Wv, Wo, ws);
  hipLaunchKernelGGL(qkv_kernel, dim3(32, 24), dim3(256), 0, stream,
                     cosp, sinp, ws);
  hipLaunchKernelGGL(attn_kernel, dim3(512), dim3(512), 98304, stream,
                     amask, ws);
  hipLaunchKernelGGL(outproj_kernel, dim3(32, 16), dim3(256), 0, stream,
                     ws, Out);
}

// Round 5
// 298.850 us; speedup vs baseline: 1.1561x; 1.1561x over previous
//
#include <hip/hip_runtime.h>
#include <hip/hip_bf16.h>
#include <cstdint>

// B=1, S=4096, HID=2048, NH=16, NKV=4, HD=128, BLK=128, LOCAL=4, GLOB=4, STRIDE=8
#define NEGV   (-1000000000.0f)
#define SCALE  0.08838834764831845f            // 128^-0.5
#define LOG2E  1.4426950408889634f
#define QSC    (SCALE * LOG2E)                 // folded into Q at qkv epilogue
#define NEGL2  (NEGV * LOG2E)                  // mask bias in exp2 domain

typedef __bf16 bf16x8 __attribute__((ext_vector_type(8)));
typedef float  f32x4  __attribute__((ext_vector_type(4)));
typedef unsigned short u16;
typedef unsigned int   u32;

#define MFMA16(a, b, c) __builtin_amdgcn_mfma_f32_16x16x32_bf16((a), (b), (c), 0, 0, 0)

// ---- workspace layout (u16 units). AOp aliases Xp (X dead after qkv GEMM).
#define WS_XP    ((size_t)0)          // X frag-order, 16 MiB
#define WS_AOP   ((size_t)0)          // attn out frag-order (alias)
#define WS_WQP   ((size_t)8388608)    // Wq^T frag-order, 8 MiB
#define WS_WKP   ((size_t)12582912)   // Wk^T frag-order, 2 MiB
#define WS_WVP   ((size_t)13631488)   // Wv^T frag-order, 2 MiB
#define WS_WOP   ((size_t)14680064)   // Wo^T frag-order, 8 MiB
#define WS_QF    ((size_t)18874368)   // Q attn-A-frag order [h][4096x128], 16 MiB
#define WS_KF    ((size_t)27262976)   // K attn-B-frag order [kvh][4096x128], 4 MiB
#define WS_VF    ((size_t)29360128)   // V attn-PV-frag order[kvh][128x4096], 4 MiB

__device__ __forceinline__ u16 f2bf(float f) {
  union { float f; u32 u; } v; v.f = f;
  u32 u = v.u;
  u += 0x7FFFu + ((u >> 16) & 1u);   // RNE
  return (u16)(u >> 16);
}

__device__ __forceinline__ void gl_lds16(const u16* g, u16* l) {
  __builtin_amdgcn_global_load_lds((const __attribute__((address_space(1))) u32*)g,
                                   (__attribute__((address_space(3))) u32*)l,
                                   16, 0, 0);
}

// fragment-order u16 offset within a 128(row) x 32(k) tile
__device__ __forceinline__ int fragoff(int row, int k) {
  return ((row >> 4) * 64 + ((k >> 3) & 3) * 16 + (row & 15)) * 8 + (k & 7);
}

// ============================================================================
// Kernel 0: one-time fp32 -> bf16 conversion into fragment-order layouts.
// ============================================================================
__global__ __launch_bounds__(256, 4)
void convert_kernel(const float* __restrict__ X,
                    const float* __restrict__ Wq,
                    const float* __restrict__ Wk,
                    const float* __restrict__ Wv,
                    const float* __restrict__ Wo,
                    u16* __restrict__ ws)
{
  const int t = blockIdx.x;
  const int tid = threadIdx.x;
  const float* src; u16* dst; int tt, ldn; bool amode = false;
  if (t < 2048)      { src = X;  dst = ws + WS_XP;  tt = t;        ldn = 2048; amode = true; }
  else if (t < 3072) { src = Wq; dst = ws + WS_WQP; tt = t - 2048; ldn = 2048; }
  else if (t < 3328) { src = Wk; dst = ws + WS_WKP; tt = t - 3072; ldn = 512;  }
  else if (t < 3584) { src = Wv; dst = ws + WS_WVP; tt = t - 3328; ldn = 512;  }
  else               { src = Wo; dst = ws + WS_WOP; tt = t - 3584; ldn = 2048; }
  const int rb = tt >> 6, kb = tt & 63;

  if (amode) {
    #pragma unroll
    for (int p = 0; p < 2; ++p) {
      const int c = tid + 256 * p;
      const int row = (c >> 6) * 16 + (c & 15);
      const int k0  = ((c >> 4) & 3) * 8;
      union { u16 h[8]; uint4 v; } pk;
      const float* s0 = src + (size_t)(rb * 128 + row) * 2048 + kb * 32 + k0;
      const float4 a0 = *reinterpret_cast<const float4*>(s0);
      const float4 a1 = *reinterpret_cast<const float4*>(s0 + 4);
      pk.h[0] = f2bf(a0.x); pk.h[1] = f2bf(a0.y); pk.h[2] = f2bf(a0.z); pk.h[3] = f2bf(a0.w);
      pk.h[4] = f2bf(a1.x); pk.h[5] = f2bf(a1.y); pk.h[6] = f2bf(a1.z); pk.h[7] = f2bf(a1.w);
      *reinterpret_cast<uint4*>(dst + (size_t)tt * 4096 + c * 8) = pk.v;
    }
  } else {
    __shared__ u16 Ls[32][136];   // [k][n], +8 pad
    #pragma unroll
    for (int i = 0; i < 4; ++i) {
      const int c = tid + 256 * i;            // 0..1023
      const int k = c >> 5, n4 = c & 31;
      const float4 wv = *reinterpret_cast<const float4*>(
          src + (size_t)(kb * 32 + k) * ldn + rb * 128 + n4 * 4);
      u16* d = &Ls[k][n4 * 4];
      d[0] = f2bf(wv.x); d[1] = f2bf(wv.y); d[2] = f2bf(wv.z); d[3] = f2bf(wv.w);
    }
    __syncthreads();
    #pragma unroll
    for (int p = 0; p < 2; ++p) {
      const int c = tid + 256 * p;
      const int row = (c >> 6) * 16 + (c & 15);
      const int k0  = ((c >> 4) & 3) * 8;
      union { u16 h[8]; uint4 v; } pk;
      #pragma unroll
      for (int j = 0; j < 8; ++j) pk.h[j] = Ls[k0 + j][row];
      *reinterpret_cast<uint4*>(dst + (size_t)tt * 4096 + c * 8) = pk.v;
    }
  }
}

// ---- shared GEMM main loop: 128x128 tile, BK=32, K=2048, frag-order inputs.
__device__ __forceinline__ void gemm_core(const u16* __restrict__ pa,
                                          const u16* __restrict__ pb,
                                          u16* As, u16* Bs,
                                          int tid, int wave, int lane,
                                          f32x4 acc[2][8])
{
  for (int it = 0; it < 64; ++it) {
    __syncthreads();
    gl_lds16(pa + tid * 8,         As + tid * 8);
    gl_lds16(pa + (tid + 256) * 8, As + (tid + 256) * 8);
    gl_lds16(pb + tid * 8,         Bs + tid * 8);
    gl_lds16(pb + (tid + 256) * 8, Bs + (tid + 256) * 8);
    pa += 4096; pb += 4096;
    __syncthreads();
    bf16x8 af0 = *reinterpret_cast<const bf16x8*>(As + (wave * 2 + 0) * 512 + lane * 8);
    bf16x8 af1 = *reinterpret_cast<const bf16x8*>(As + (wave * 2 + 1) * 512 + lane * 8);
    #pragma unroll
    for (int nt = 0; nt < 8; ++nt) {
      const bf16x8 bfr = *reinterpret_cast<const bf16x8*>(Bs + nt * 512 + lane * 8);
      acc[0][nt] = MFMA16(af0, bfr, acc[0][nt]);
      acc[1][nt] = MFMA16(af1, bfr, acc[1][nt]);
    }
  }
}

// ============================================================================
// Kernel 1: QKV GEMM + fused RoPE -> attention frag-order outputs.
// Q pre-scaled by SCALE*log2(e): attention softmax runs in exp2 domain.
// launch_bounds(256,3): 12 waves/CU, grid 768 = one 3-resident round.
// ============================================================================
__global__ __launch_bounds__(256, 3)
void qkv_kernel(const float* __restrict__ cosp,
                const float* __restrict__ sinp,
                u16* __restrict__ ws)
{
  const int mb = blockIdx.x, bn = blockIdx.y;
  const int tid = threadIdx.x;
  const int wave = tid >> 6, lane = tid & 63;
  const int lq = lane >> 4, l16 = lane & 15;

  const u16* Ab = ws + WS_XP + (size_t)mb * 64 * 4096;
  const u16* Bb; int seg, hh;
  if (bn < 16)      { Bb = ws + WS_WQP + (size_t)bn * 64 * 4096;        seg = 0; hh = bn; }
  else if (bn < 20) { Bb = ws + WS_WKP + (size_t)(bn - 16) * 64 * 4096; seg = 1; hh = bn - 16; }
  else              { Bb = ws + WS_WVP + (size_t)(bn - 20) * 64 * 4096; seg = 2; hh = bn - 20; }

  __shared__ __align__(16) u16 As[4096];
  __shared__ __align__(16) u16 Bs[4096];

  f32x4 acc[2][8];
  #pragma unroll
  for (int i = 0; i < 2; ++i)
    #pragma unroll
    for (int j = 0; j < 8; ++j)
      #pragma unroll
      for (int r = 0; r < 4; ++r) acc[i][j][r] = 0.0f;

  gemm_core(Ab, Bb, As, Bs, tid, wave, lane, acc);

  const int m0 = mb * 128;
  if (seg == 2) {          // V -> PV B-frag order (rows=d, k=t)
    u16* V = ws + WS_VF + (size_t)hh * 524288;
    #pragma unroll
    for (int mt = 0; mt < 2; ++mt)
      #pragma unroll
      for (int nt = 0; nt < 8; ++nt) {
        const int d = nt * 16 + l16;
        #pragma unroll
        for (int r = 0; r < 4; ++r) {
          const int s = m0 + wave * 32 + mt * 16 + lq * 4 + r;
          V[(s >> 5) * 4096 + fragoff(d, s & 31)] = f2bf(acc[mt][nt][r]);
        }
      }
  } else {                 // Q/K + RoPE (cos[d+64]==cos[d]); Q also *QSC
    u16* D = ws + ((seg == 0) ? WS_QF : WS_KF) + (size_t)hh * 524288;
    const float qs = (seg == 0) ? QSC : 1.0f;
    #pragma unroll
    for (int mt = 0; mt < 2; ++mt)
      #pragma unroll
      for (int r = 0; r < 4; ++r) {
        const int s = m0 + wave * 32 + mt * 16 + lq * 4 + r;
        const int sl = s & 127;
        u16* Dt = D + (size_t)(s >> 7) * 16384;
        #pragma unroll
        for (int nt = 0; nt < 4; ++nt) {
          const int d1 = nt * 16 + l16, d2 = d1 + 64;
          const float c  = cosp[s * 128 + d1];
          const float sn = sinp[s * 128 + d1];
          const float v1 = acc[mt][nt][r], v2 = acc[mt][nt + 4][r];
          Dt[(d1 >> 5) * 4096 + fragoff(sl, d1 & 31)] = f2bf((v1 * c - v2 * sn) * qs);
          Dt[(d2 >> 5) * 4096 + fragoff(sl, d2 & 31)] = f2bf((v2 * c + v1 * sn) * qs);
        }
      }
  }
}

// ============================================================================
// Kernel 2: block-sparse attention (R3 structure — the 73 µs configuration).
// 512 thr = 8 waves x 16 q-rows; static 64 KB LDS; DMA staging; skip invalid
// key-blocks; exp2-domain softmax (Q pre-scaled; NO register prefetch —
// R4 showed it spills to scratch: WRITE_SIZE 29->198 MB).
// ============================================================================
__global__ __launch_bounds__(512, 4)
void attn_kernel(const float* __restrict__ amask, u16* __restrict__ ws)
{
  const int n = blockIdx.x, h = blockIdx.y;
  const int kvh = h >> 2;
  const int tid = threadIdx.x;
  const int wave = tid >> 6, lane = tid & 63;
  const int lq = lane >> 4, l16 = lane & 15;

  const u16* Kfb = ws + WS_KF + (size_t)kvh * 524288;
  const u16* Vfb = ws + WS_VF + (size_t)kvh * 524288;
  u16* AOp = ws + WS_AOP;

  __shared__ __align__(16) u16 bufK[16384];  // K tile (B-frag); then P (A-frag)
  __shared__ __align__(16) u16 bufV[16384];  // V tile (PV B-frag)

  const u16* Qb = ws + WS_QF + (size_t)h * 524288 + (size_t)n * 16384;
  bf16x8 qf[4];
  #pragma unroll
  for (int kk = 0; kk < 4; ++kk)
    qf[kk] = *reinterpret_cast<const bf16x8*>(Qb + (size_t)kk * 4096 + (wave * 64 + lane) * 8);

  f32x4 O[8];
  #pragma unroll
  for (int j = 0; j < 8; ++j)
    #pragma unroll
    for (int r = 0; r < 4; ++r) O[j][r] = 0.0f;
  float mrow[4], lrow[4];
  #pragma unroll
  for (int r = 0; r < 4; ++r) { mrow[r] = -3.0e38f; lrow[r] = 0.0f; }

  // global block indices + dup validity (reference semantics, verified R1-R4)
  int gidx[4]; bool gval[4];
  gidx[0] = 0;
  gidx[1] = (n - 24 > 0) ? n - 24 : 0;
  gidx[2] = (n - 16 > 0) ? n - 16 : 0;
  gidx[3] = (n - 8  > 0) ? n - 8  : 0;
  gval[0] = true;
  gval[1] = (gidx[1] != gidx[0]);
  gval[2] = (gidx[2] != gidx[1]);
  gval[3] = (gidx[3] != gidx[2]);

  for (int kb = 0; kb < 8; ++kb) {
    int bkey; bool bvalid; bool intra;
    if (kb < 4) { bkey = n - 3 + kb; bvalid = (bkey >= 0); intra = (kb == 3); }
    else        { bkey = gidx[kb - 4]; bvalid = gval[kb - 4]; intra = false; }
    if (!bvalid) continue;   // exact: these blocks contribute 0 probability

    const u16* Kb = Kfb + (size_t)bkey * 16384;
    const u16* Vb = Vfb + (size_t)bkey * 16384;
    __syncthreads();                 // prior P/V reads done before restage
    #pragma unroll
    for (int p = 0; p < 4; ++p) {
      gl_lds16(Kb + (tid + 512 * p) * 8, bufK + (tid + 512 * p) * 8);
      gl_lds16(Vb + (tid + 512 * p) * 8, bufV + (tid + 512 * p) * 8);
    }
    __syncthreads();

    // S = Q K^T (Q pre-scaled; scores in exp2 domain)
    f32x4 sacc[8];
    #pragma unroll
    for (int j = 0; j < 8; ++j)
      #pragma unroll
      for (int r = 0; r < 4; ++r) sacc[j][r] = 0.0f;
    #pragma unroll
    for (int kk = 0; kk < 4; ++kk)
      #pragma unroll
      for (int nt = 0; nt < 8; ++nt) {
        const bf16x8 bfr = *reinterpret_cast<const bf16x8*>(
            bufK + ((kk * 8 + nt) * 64 + lane) * 8);
        sacc[nt] = MFMA16(qf[kk], bfr, sacc[nt]);
      }

    float bias[8];
    #pragma unroll
    for (int nt = 0; nt < 8; ++nt)
      bias[nt] = (1.0f - amask[bkey * 128 + nt * 16 + l16]) * NEGL2;

    __syncthreads();                 // all waves done reading K before P write

    u16* pw = bufK + wave * 2048;    // per-wave 16x128 P region, A-frag order
    #pragma unroll
    for (int r = 0; r < 4; ++r) {
      const int tq = wave * 16 + lq * 4 + r;
      float sv[8];
      float rmax = -3.0e38f;
      #pragma unroll
      for (int nt = 0; nt < 8; ++nt) {
        float s = sacc[nt][r] + bias[nt];
        const int tk = nt * 16 + l16;
        if (intra && tk > tq) s += NEGL2;
        sv[nt] = s;
        rmax = fmaxf(rmax, s);
      }
      #pragma unroll
      for (int off = 1; off < 16; off <<= 1)
        rmax = fmaxf(rmax, __shfl_xor(rmax, off, 64));
      const float mold = mrow[r];
      const float mnew = fmaxf(mold, rmax);
      const float alpha = exp2f(mold - mnew);
      float rsum = 0.0f;
      u16 pb[8];
      #pragma unroll
      for (int nt = 0; nt < 8; ++nt) {
        const float pe = exp2f(sv[nt] - mnew);
        rsum += pe;
        pb[nt] = f2bf(pe);
      }
      #pragma unroll
      for (int off = 1; off < 16; off <<= 1)
        rsum += __shfl_xor(rsum, off, 64);
      lrow[r] = lrow[r] * alpha + rsum;
      mrow[r] = mnew;
      #pragma unroll
      for (int nt = 0; nt < 8; ++nt) O[nt][r] *= alpha;
      // scatter P into A-frag order: elem(m=lq*4+r, k=nt*16+l16)
      #pragma unroll
      for (int nt = 0; nt < 8; ++nt)
        pw[(nt >> 1) * 512 + ((((nt & 1) * 2 + (l16 >> 3)) * 16) + lq * 4 + r) * 8 + (l16 & 7)] = pb[nt];
    }

    // O += P @ V (own-wave P region; no barrier needed)
    #pragma unroll
    for (int kk = 0; kk < 4; ++kk) {
      const bf16x8 pf = *reinterpret_cast<const bf16x8*>(pw + kk * 512 + lane * 8);
      #pragma unroll
      for (int nt = 0; nt < 8; ++nt) {
        const bf16x8 vfr = *reinterpret_cast<const bf16x8*>(
            bufV + ((kk * 8 + nt) * 64 + lane) * 8);
        O[nt] = MFMA16(pf, vfr, O[nt]);
      }
    }
  }

  // finalize: write AO in outproj A-frag order
  #pragma unroll
  for (int r = 0; r < 4; ++r) {
    const float inv = 1.0f / lrow[r];
    const int s = n * 128 + wave * 16 + lq * 4 + r;
    #pragma unroll
    for (int nt = 0; nt < 8; ++nt) {
      const int kcol = h * 128 + nt * 16 + l16;
      AOp[((size_t)(s >> 7) * 64 + (kcol >> 5)) * 4096 + fragoff(s & 127, kcol & 31)] =
          f2bf(O[nt][r] * inv);
    }
  }
}

// ============================================================================
// Kernel 3: output projection. AOp fragorder @ Wop fragorder -> Out fp32.
// ============================================================================
__global__ __launch_bounds__(256, 3)
void outproj_kernel(const u16* __restrict__ ws, float* __restrict__ Out)
{
  const int mb = blockIdx.x, bn = blockIdx.y;
  const int tid = threadIdx.x;
  const int wave = tid >> 6, lane = tid & 63;
  const int lq = lane >> 4, l16 = lane & 15;

  const u16* Ab = ws + WS_AOP + (size_t)mb * 64 * 4096;
  const u16* Bb = ws + WS_WOP + (size_t)bn * 64 * 4096;

  __shared__ __align__(16) u16 As[4096];
  __shared__ __align__(16) u16 Bs[4096];

  f32x4 acc[2][8];
  #pragma unroll
  for (int i = 0; i < 2; ++i)
    #pragma unroll
    for (int j = 0; j < 8; ++j)
      #pragma unroll
      for (int r = 0; r < 4; ++r) acc[i][j][r] = 0.0f;

  gemm_core(Ab, Bb, (u16*)As, (u16*)Bs, tid, wave, lane, acc);

  #pragma unroll
  for (int mt = 0; mt < 2; ++mt)
    #pragma unroll
    for (int nt = 0; nt < 8; ++nt) {
      const int ccol = bn * 128 + nt * 16 + l16;
      #pragma unroll
      for (int r = 0; r < 4; ++r) {
        const int s = mb * 128 + wave * 32 + mt * 16 + lq * 4 + r;
        Out[(size_t)s * 2048 + ccol] = acc[mt][nt][r];
      }
    }
}

// ============================================================================
extern "C" void kernel_launch(void* const* d_in, const int* in_sizes, int n_in,
                              void* d_out, int out_size, void* d_ws, size_t ws_size,
                              hipStream_t stream) {
  const float* X     = (const float*)d_in[0];
  const float* amask = (const float*)d_in[1];
  const float* cosp  = (const float*)d_in[2];
  const float* sinp  = (const float*)d_in[3];
  const float* Wq    = (const float*)d_in[4];
  const float* Wk    = (const float*)d_in[5];
  const float* Wv    = (const float*)d_in[6];
  const float* Wo    = (const float*)d_in[7];
  float* Out = (float*)d_out;
  u16* ws = (u16*)d_ws;

  hipLaunchKernelGGL(convert_kernel, dim3(4608), dim3(256), 0, stream,
                     X, Wq, Wk, Wv, Wo, ws);
  hipLaunchKernelGGL(qkv_kernel, dim3(32, 24), dim3(256), 0, stream,
                     cosp, sinp, ws);
  hipLaunchKernelGGL(attn_kernel, dim3(32, 16), dim3(512), 0, stream,
                     amask, ws);
  hipLaunchKernelGGL(outproj_kernel, dim3(32, 16), dim3(256), 0, stream,
                     ws, Out);
}

// Round 6
// 298.598 us; speedup vs baseline: 1.1571x; 1.0008x over previous
//
#include <hip/hip_runtime.h>
#include <hip/hip_bf16.h>
#include <cstdint>

// B=1, S=4096, HID=2048, NH=16, NKV=4, HD=128, BLK=128, LOCAL=4, GLOB=4, STRIDE=8
#define NEGV   (-1000000000.0f)
#define SCALE  0.08838834764831845f            // 128^-0.5
#define LOG2E  1.4426950408889634f
#define QSC    (SCALE * LOG2E)                 // folded into Q at qkv epilogue
#define NEGL2  (NEGV * LOG2E)                  // mask bias in exp2 domain

typedef __bf16 bf16x8 __attribute__((ext_vector_type(8)));
typedef float  f32x4  __attribute__((ext_vector_type(4)));
typedef unsigned short u16;
typedef unsigned int   u32;

#define MFMA16(a, b, c) __builtin_amdgcn_mfma_f32_16x16x32_bf16((a), (b), (c), 0, 0, 0)

// ---- workspace layout (u16 units). AOp aliases Xp (X dead after qkv GEMM).
#define WS_XP    ((size_t)0)          // X frag-order, 16 MiB
#define WS_AOP   ((size_t)0)          // attn out frag-order (alias)
#define WS_WQP   ((size_t)8388608)    // Wq^T frag-order, 8 MiB
#define WS_WKP   ((size_t)12582912)   // Wk^T frag-order, 2 MiB
#define WS_WVP   ((size_t)13631488)   // Wv^T frag-order, 2 MiB
#define WS_WOP   ((size_t)14680064)   // Wo^T frag-order, 8 MiB
#define WS_QF    ((size_t)18874368)   // Q attn-A-frag order [h][4096x128], 16 MiB
#define WS_KF    ((size_t)27262976)   // K attn-B-frag order [kvh][4096x128], 4 MiB
#define WS_VF    ((size_t)29360128)   // V attn-PV-frag order[kvh][128x4096], 4 MiB

__device__ __forceinline__ u16 f2bf(float f) {
  union { float f; u32 u; } v; v.f = f;
  u32 u = v.u;
  u += 0x7FFFu + ((u >> 16) & 1u);   // RNE
  return (u16)(u >> 16);
}

__device__ __forceinline__ void gl_lds16(const u16* g, u16* l) {
  __builtin_amdgcn_global_load_lds((const __attribute__((address_space(1))) u32*)g,
                                   (__attribute__((address_space(3))) u32*)l,
                                   16, 0, 0);
}

// fragment-order u16 offset within a 128(row) x 32(k) tile
__device__ __forceinline__ int fragoff(int row, int k) {
  return ((row >> 4) * 64 + ((k >> 3) & 3) * 16 + (row & 15)) * 8 + (k & 7);
}

// ============================================================================
// Kernel 0: one-time fp32 -> bf16 conversion into fragment-order layouts.
// ============================================================================
__global__ __launch_bounds__(256, 4)
void convert_kernel(const float* __restrict__ X,
                    const float* __restrict__ Wq,
                    const float* __restrict__ Wk,
                    const float* __restrict__ Wv,
                    const float* __restrict__ Wo,
                    u16* __restrict__ ws)
{
  const int t = blockIdx.x;
  const int tid = threadIdx.x;
  const float* src; u16* dst; int tt, ldn; bool amode = false;
  if (t < 2048)      { src = X;  dst = ws + WS_XP;  tt = t;        ldn = 2048; amode = true; }
  else if (t < 3072) { src = Wq; dst = ws + WS_WQP; tt = t - 2048; ldn = 2048; }
  else if (t < 3328) { src = Wk; dst = ws + WS_WKP; tt = t - 3072; ldn = 512;  }
  else if (t < 3584) { src = Wv; dst = ws + WS_WVP; tt = t - 3328; ldn = 512;  }
  else               { src = Wo; dst = ws + WS_WOP; tt = t - 3584; ldn = 2048; }
  const int rb = tt >> 6, kb = tt & 63;

  if (amode) {
    #pragma unroll
    for (int p = 0; p < 2; ++p) {
      const int c = tid + 256 * p;
      const int row = (c >> 6) * 16 + (c & 15);
      const int k0  = ((c >> 4) & 3) * 8;
      union { u16 h[8]; uint4 v; } pk;
      const float* s0 = src + (size_t)(rb * 128 + row) * 2048 + kb * 32 + k0;
      const float4 a0 = *reinterpret_cast<const float4*>(s0);
      const float4 a1 = *reinterpret_cast<const float4*>(s0 + 4);
      pk.h[0] = f2bf(a0.x); pk.h[1] = f2bf(a0.y); pk.h[2] = f2bf(a0.z); pk.h[3] = f2bf(a0.w);
      pk.h[4] = f2bf(a1.x); pk.h[5] = f2bf(a1.y); pk.h[6] = f2bf(a1.z); pk.h[7] = f2bf(a1.w);
      *reinterpret_cast<uint4*>(dst + (size_t)tt * 4096 + c * 8) = pk.v;
    }
  } else {
    __shared__ u16 Ls[32][136];   // [k][n], +8 pad
    #pragma unroll
    for (int i = 0; i < 4; ++i) {
      const int c = tid + 256 * i;            // 0..1023
      const int k = c >> 5, n4 = c & 31;
      const float4 wv = *reinterpret_cast<const float4*>(
          src + (size_t)(kb * 32 + k) * ldn + rb * 128 + n4 * 4);
      u16* d = &Ls[k][n4 * 4];
      d[0] = f2bf(wv.x); d[1] = f2bf(wv.y); d[2] = f2bf(wv.z); d[3] = f2bf(wv.w);
    }
    __syncthreads();
    #pragma unroll
    for (int p = 0; p < 2; ++p) {
      const int c = tid + 256 * p;
      const int row = (c >> 6) * 16 + (c & 15);
      const int k0  = ((c >> 4) & 3) * 8;
      union { u16 h[8]; uint4 v; } pk;
      #pragma unroll
      for (int j = 0; j < 8; ++j) pk.h[j] = Ls[k0 + j][row];
      *reinterpret_cast<uint4*>(dst + (size_t)tt * 4096 + c * 8) = pk.v;
    }
  }
}

// ---- shared GEMM main loop: 128x128 tile, BK=32, K=2048, frag-order inputs.
__device__ __forceinline__ void gemm_core(const u16* __restrict__ pa,
                                          const u16* __restrict__ pb,
                                          u16* As, u16* Bs,
                                          int tid, int wave, int lane,
                                          f32x4 acc[2][8])
{
  for (int it = 0; it < 64; ++it) {
    __syncthreads();
    gl_lds16(pa + tid * 8,         As + tid * 8);
    gl_lds16(pa + (tid + 256) * 8, As + (tid + 256) * 8);
    gl_lds16(pb + tid * 8,         Bs + tid * 8);
    gl_lds16(pb + (tid + 256) * 8, Bs + (tid + 256) * 8);
    pa += 4096; pb += 4096;
    __syncthreads();
    bf16x8 af0 = *reinterpret_cast<const bf16x8*>(As + (wave * 2 + 0) * 512 + lane * 8);
    bf16x8 af1 = *reinterpret_cast<const bf16x8*>(As + (wave * 2 + 1) * 512 + lane * 8);
    #pragma unroll
    for (int nt = 0; nt < 8; ++nt) {
      const bf16x8 bfr = *reinterpret_cast<const bf16x8*>(Bs + nt * 512 + lane * 8);
      acc[0][nt] = MFMA16(af0, bfr, acc[0][nt]);
      acc[1][nt] = MFMA16(af1, bfr, acc[1][nt]);
    }
  }
}

// ============================================================================
// Kernel 1: QKV GEMM + fused RoPE -> attention frag-order outputs.
// Q pre-scaled by SCALE*log2(e): attention softmax runs in exp2 domain.
// ============================================================================
__global__ __launch_bounds__(256, 3)
void qkv_kernel(const float* __restrict__ cosp,
                const float* __restrict__ sinp,
                u16* __restrict__ ws)
{
  const int mb = blockIdx.x, bn = blockIdx.y;
  const int tid = threadIdx.x;
  const int wave = tid >> 6, lane = tid & 63;
  const int lq = lane >> 4, l16 = lane & 15;

  const u16* Ab = ws + WS_XP + (size_t)mb * 64 * 4096;
  const u16* Bb; int seg, hh;
  if (bn < 16)      { Bb = ws + WS_WQP + (size_t)bn * 64 * 4096;        seg = 0; hh = bn; }
  else if (bn < 20) { Bb = ws + WS_WKP + (size_t)(bn - 16) * 64 * 4096; seg = 1; hh = bn - 16; }
  else              { Bb = ws + WS_WVP + (size_t)(bn - 20) * 64 * 4096; seg = 2; hh = bn - 20; }

  __shared__ __align__(16) u16 As[4096];
  __shared__ __align__(16) u16 Bs[4096];

  f32x4 acc[2][8];
  #pragma unroll
  for (int i = 0; i < 2; ++i)
    #pragma unroll
    for (int j = 0; j < 8; ++j)
      #pragma unroll
      for (int r = 0; r < 4; ++r) acc[i][j][r] = 0.0f;

  gemm_core(Ab, Bb, As, Bs, tid, wave, lane, acc);

  const int m0 = mb * 128;
  if (seg == 2) {          // V -> PV B-frag order (rows=d, k=t)
    u16* V = ws + WS_VF + (size_t)hh * 524288;
    #pragma unroll
    for (int mt = 0; mt < 2; ++mt)
      #pragma unroll
      for (int nt = 0; nt < 8; ++nt) {
        const int d = nt * 16 + l16;
        #pragma unroll
        for (int r = 0; r < 4; ++r) {
          const int s = m0 + wave * 32 + mt * 16 + lq * 4 + r;
          V[(s >> 5) * 4096 + fragoff(d, s & 31)] = f2bf(acc[mt][nt][r]);
        }
      }
  } else {                 // Q/K + RoPE (cos[d+64]==cos[d]); Q also *QSC
    u16* D = ws + ((seg == 0) ? WS_QF : WS_KF) + (size_t)hh * 524288;
    const float qs = (seg == 0) ? QSC : 1.0f;
    #pragma unroll
    for (int mt = 0; mt < 2; ++mt)
      #pragma unroll
      for (int r = 0; r < 4; ++r) {
        const int s = m0 + wave * 32 + mt * 16 + lq * 4 + r;
        const int sl = s & 127;
        u16* Dt = D + (size_t)(s >> 7) * 16384;
        #pragma unroll
        for (int nt = 0; nt < 4; ++nt) {
          const int d1 = nt * 16 + l16, d2 = d1 + 64;
          const float c  = cosp[s * 128 + d1];
          const float sn = sinp[s * 128 + d1];
          const float v1 = acc[mt][nt][r], v2 = acc[mt][nt + 4][r];
          Dt[(d1 >> 5) * 4096 + fragoff(sl, d1 & 31)] = f2bf((v1 * c - v2 * sn) * qs);
          Dt[(d2 >> 5) * 4096 + fragoff(sl, d2 & 31)] = f2bf((v2 * c + v1 * sn) * qs);
        }
      }
  }
}

// ============================================================================
// Kernel 2: block-sparse attention — single-barrier double-buffered design.
// Grid 256 (one block per CU, fully resident): block = (n, kvh, head-pair).
// 512 thr = 8 waves; wave owns 32 q-rows (2 MFMA row-tiles) of one q-head.
// LDS 144 KB dynamic: K/V double buffers (2x32K) + wave-private chunked P.
// DMA for kb i+1 issued right after the single per-iter barrier (in flight
// during compute). NO global->register prefetch (R4 spill trap).
// ============================================================================
__global__ __launch_bounds__(512, 2)
void attn_kernel(const float* __restrict__ amask, u16* __restrict__ ws)
{
  extern __shared__ __align__(16) u16 smem[];
  // [buf0: K 16384 | V 16384][buf1: K 16384 | V 16384][P: 8 x 1024]
  const int bx  = blockIdx.x;
  const int n   = bx >> 3;
  const int sub = bx & 7;
  const int kvh = sub >> 1;
  const int tid = threadIdx.x;
  const int wave = tid >> 6, lane = tid & 63;
  const int lq = lane >> 4, l16 = lane & 15;
  const int h = kvh * 4 + (sub & 1) * 2 + (wave >> 2);   // q-head of this wave
  const int wq = wave & 3;                               // 32-row group in head

  const u16* Kfb = ws + WS_KF + (size_t)kvh * 524288;
  const u16* Vfb = ws + WS_VF + (size_t)kvh * 524288;
  u16* AOp = ws + WS_AOP;
  u16* Pw = smem + 65536 + wave * 1024;   // wave-private 32x32-key P chunk

  // Q A-fragments: rows wq*32 + mt*16
  const u16* Qb = ws + WS_QF + (size_t)h * 524288 + (size_t)n * 16384;
  bf16x8 qf[2][4];
  #pragma unroll
  for (int mt = 0; mt < 2; ++mt)
    #pragma unroll
    for (int kk = 0; kk < 4; ++kk)
      qf[mt][kk] = *reinterpret_cast<const bf16x8*>(
          Qb + (size_t)kk * 4096 + ((wq * 2 + mt) * 64 + lane) * 8);

  f32x4 O[2][8];
  #pragma unroll
  for (int i = 0; i < 2; ++i)
    #pragma unroll
    for (int j = 0; j < 8; ++j)
      #pragma unroll
      for (int r = 0; r < 4; ++r) O[i][j][r] = 0.0f;
  float mrow[2][4], lrow[2][4];
  #pragma unroll
  for (int i = 0; i < 2; ++i)
    #pragma unroll
    for (int r = 0; r < 4; ++r) { mrow[i][r] = -3.0e38f; lrow[i][r] = 0.0f; }

  // closed-form valid-kb list (reference semantics, verified R1-R5)
  const int L = (n < 3 ? n : 3) + 1;
  const int G = (n >= 25) ? 3 : (n >= 17) ? 2 : (n >= 9) ? 1 : 0;
  const int nv = L + 1 + G;
  #define KBOF(i) ((i) < L ? n - L + 1 + (i) : ((i) == L ? 0 : n - 8 * (G - ((i) - L - 1))))

  // prologue: DMA kb 0 into buf 0
  int nxt = KBOF(0);
  {
    const u16* Kb = Kfb + (size_t)nxt * 16384;
    const u16* Vb = Vfb + (size_t)nxt * 16384;
    #pragma unroll
    for (int p = 0; p < 4; ++p) {
      gl_lds16(Kb + (tid + 512 * p) * 8, smem + (tid + 512 * p) * 8);
      gl_lds16(Vb + (tid + 512 * p) * 8, smem + 16384 + (tid + 512 * p) * 8);
    }
  }

  for (int i = 0; i < nv; ++i) {
    const int cur = i & 1;
    const int bcur = nxt;
    const bool intra = (i == L - 1);
    u16* bufK = smem + cur * 32768;
    u16* bufV = bufK + 16384;

    __syncthreads();   // drains own DMA (vmcnt) -> buf[cur] ready; prior
                       // iter's readers of buf[cur^1] are all past this point

    if (i + 1 < nv) {  // launch next DMA into the other buffer (async)
      nxt = KBOF(i + 1);
      const u16* Kb = Kfb + (size_t)nxt * 16384;
      const u16* Vb = Vfb + (size_t)nxt * 16384;
      u16* dK = smem + (cur ^ 1) * 32768;
      #pragma unroll
      for (int p = 0; p < 4; ++p) {
        gl_lds16(Kb + (tid + 512 * p) * 8, dK + (tid + 512 * p) * 8);
        gl_lds16(Vb + (tid + 512 * p) * 8, dK + 16384 + (tid + 512 * p) * 8);
      }
    }

    float bias[8];
    #pragma unroll
    for (int nt = 0; nt < 8; ++nt)
      bias[nt] = (1.0f - amask[bcur * 128 + nt * 16 + l16]) * NEGL2;

    // S = Q K^T (both row-tiles share each K B-frag read)
    f32x4 sacc[2][8];
    #pragma unroll
    for (int j = 0; j < 8; ++j)
      #pragma unroll
      for (int r = 0; r < 4; ++r) { sacc[0][j][r] = 0.0f; sacc[1][j][r] = 0.0f; }
    #pragma unroll
    for (int kk = 0; kk < 4; ++kk)
      #pragma unroll
      for (int nt = 0; nt < 8; ++nt) {
        const bf16x8 bfr = *reinterpret_cast<const bf16x8*>(
            bufK + ((kk * 8 + nt) * 64 + lane) * 8);
        sacc[0][nt] = MFMA16(qf[0][kk], bfr, sacc[0][nt]);
        sacc[1][nt] = MFMA16(qf[1][kk], bfr, sacc[1][nt]);
      }

    // online softmax (exp2 domain); keep P values in registers
    u16 pbv[2][4][8];
    #pragma unroll
    for (int mt = 0; mt < 2; ++mt)
      #pragma unroll
      for (int r = 0; r < 4; ++r) {
        const int tq = wq * 32 + mt * 16 + lq * 4 + r;
        float sv[8];
        float rmax = -3.0e38f;
        #pragma unroll
        for (int nt = 0; nt < 8; ++nt) {
          float s = sacc[mt][nt][r] + bias[nt];
          const int tk = nt * 16 + l16;
          if (intra && tk > tq) s += NEGL2;
          sv[nt] = s;
          rmax = fmaxf(rmax, s);
        }
        #pragma unroll
        for (int off = 1; off < 16; off <<= 1)
          rmax = fmaxf(rmax, __shfl_xor(rmax, off, 64));
        const float mold = mrow[mt][r];
        const float mnew = fmaxf(mold, rmax);
        const float alpha = exp2f(mold - mnew);
        float rsum = 0.0f;
        #pragma unroll
        for (int nt = 0; nt < 8; ++nt) {
          const float pe = exp2f(sv[nt] - mnew);
          rsum += pe;
          pbv[mt][r][nt] = f2bf(pe);
        }
        #pragma unroll
        for (int off = 1; off < 16; off <<= 1)
          rsum += __shfl_xor(rsum, off, 64);
        lrow[mt][r] = lrow[mt][r] * alpha + rsum;
        mrow[mt][r] = mnew;
        #pragma unroll
        for (int nt = 0; nt < 8; ++nt) O[mt][nt][r] *= alpha;
      }

    // O += P @ V in 32-key chunks through the wave-private P region.
    // In-wave DS ops execute in order -> write/read/overwrite is safe.
    #pragma unroll
    for (int c = 0; c < 4; ++c) {
      #pragma unroll
      for (int mt = 0; mt < 2; ++mt)
        #pragma unroll
        for (int r = 0; r < 4; ++r)
          #pragma unroll
          for (int j = 0; j < 2; ++j) {   // nt = 2c+j
            const int nt = 2 * c + j;
            Pw[mt * 512 + ((j * 2 + (l16 >> 3)) * 16 + lq * 4 + r) * 8 + (l16 & 7)] =
                pbv[mt][r][nt];
          }
      const bf16x8 pf0 = *reinterpret_cast<const bf16x8*>(Pw + lane * 8);
      const bf16x8 pf1 = *reinterpret_cast<const bf16x8*>(Pw + 512 + lane * 8);
      #pragma unroll
      for (int nt = 0; nt < 8; ++nt) {
        const bf16x8 vfr = *reinterpret_cast<const bf16x8*>(
            bufV + ((c * 8 + nt) * 64 + lane) * 8);
        O[0][nt] = MFMA16(pf0, vfr, O[0][nt]);
        O[1][nt] = MFMA16(pf1, vfr, O[1][nt]);
      }
    }
  }
  #undef KBOF

  // finalize: write AO in outproj A-frag order
  #pragma unroll
  for (int mt = 0; mt < 2; ++mt)
    #pragma unroll
    for (int r = 0; r < 4; ++r) {
      const float inv = 1.0f / lrow[mt][r];
      const int s = n * 128 + wq * 32 + mt * 16 + lq * 4 + r;
      #pragma unroll
      for (int nt = 0; nt < 8; ++nt) {
        const int kcol = h * 128 + nt * 16 + l16;
        AOp[((size_t)(s >> 7) * 64 + (kcol >> 5)) * 4096 + fragoff(s & 127, kcol & 31)] =
            f2bf(O[mt][nt][r] * inv);
      }
    }
}

// ============================================================================
// Kernel 3: output projection. AOp fragorder @ Wop fragorder -> Out fp32.
// ============================================================================
__global__ __launch_bounds__(256, 3)
void outproj_kernel(const u16* __restrict__ ws, float* __restrict__ Out)
{
  const int mb = blockIdx.x, bn = blockIdx.y;
  const int tid = threadIdx.x;
  const int wave = tid >> 6, lane = tid & 63;
  const int lq = lane >> 4, l16 = lane & 15;

  const u16* Ab = ws + WS_AOP + (size_t)mb * 64 * 4096;
  const u16* Bb = ws + WS_WOP + (size_t)bn * 64 * 4096;

  __shared__ __align__(16) u16 As[4096];
  __shared__ __align__(16) u16 Bs[4096];

  f32x4 acc[2][8];
  #pragma unroll
  for (int i = 0; i < 2; ++i)
    #pragma unroll
    for (int j = 0; j < 8; ++j)
      #pragma unroll
      for (int r = 0; r < 4; ++r) acc[i][j][r] = 0.0f;

  gemm_core(Ab, Bb, (u16*)As, (u16*)Bs, tid, wave, lane, acc);

  #pragma unroll
  for (int mt = 0; mt < 2; ++mt)
    #pragma unroll
    for (int nt = 0; nt < 8; ++nt) {
      const int ccol = bn * 128 + nt * 16 + l16;
      #pragma unroll
      for (int r = 0; r < 4; ++r) {
        const int s = mb * 128 + wave * 32 + mt * 16 + lq * 4 + r;
        Out[(size_t)s * 2048 + ccol] = acc[mt][nt][r];
      }
    }
}

// ============================================================================
extern "C" void kernel_launch(void* const* d_in, const int* in_sizes, int n_in,
                              void* d_out, int out_size, void* d_ws, size_t ws_size,
                              hipStream_t stream) {
  const float* X     = (const float*)d_in[0];
  const float* amask = (const float*)d_in[1];
  const float* cosp  = (const float*)d_in[2];
  const float* sinp  = (const float*)d_in[3];
  const float* Wq    = (const float*)d_in[4];
  const float* Wk    = (const float*)d_in[5];
  const float* Wv    = (const float*)d_in[6];
  const float* Wo    = (const float*)d_in[7];
  float* Out = (float*)d_out;
  u16* ws = (u16*)d_ws;

  (void)hipFuncSetAttribute((const void*)attn_kernel,
                            hipFuncAttributeMaxDynamicSharedMemorySize, 147456);

  hipLaunchKernelGGL(convert_kernel, dim3(4608), dim3(256), 0, stream,
                     X, Wq, Wk, Wv, Wo, ws);
  hipLaunchKernelGGL(qkv_kernel, dim3(32, 24), dim3(256), 0, stream,
                     cosp, sinp, ws);
  hipLaunchKernelGGL(attn_kernel, dim3(256), dim3(512), 147456, stream,
                     amask, ws);
  hipLaunchKernelGGL(outproj_kernel, dim3(32, 16), dim3(256), 0, stream,
                     ws, Out);
}

// Round 7
// 286.102 us; speedup vs baseline: 1.2076x; 1.0437x over previous
//
#include <hip/hip_runtime.h>
#include <hip/hip_bf16.h>
#include <cstdint>

// B=1, S=4096, HID=2048, NH=16, NKV=4, HD=128, BLK=128, LOCAL=4, GLOB=4, STRIDE=8
#define NEGV   (-1000000000.0f)
#define SCALE  0.08838834764831845f            // 128^-0.5
#define LOG2E  1.4426950408889634f
#define QSC    (SCALE * LOG2E)                 // folded into Q at qkv epilogue
#define NEGL2  (NEGV * LOG2E)                  // mask bias in exp2 domain

typedef __bf16 bf16x8 __attribute__((ext_vector_type(8)));
typedef float  f32x4  __attribute__((ext_vector_type(4)));
typedef unsigned short u16;
typedef unsigned int   u32;

#define MFMA16(a, b, c) __builtin_amdgcn_mfma_f32_16x16x32_bf16((a), (b), (c), 0, 0, 0)

// ---- workspace layout (u16 units). AOp aliases Xp (X dead after qkv GEMM).
#define WS_XP    ((size_t)0)          // X frag-order, 16 MiB
#define WS_AOP   ((size_t)0)          // attn out frag-order (alias)
#define WS_WQP   ((size_t)8388608)    // Wq^T frag-order, 8 MiB
#define WS_WKP   ((size_t)12582912)   // Wk^T frag-order, 2 MiB
#define WS_WVP   ((size_t)13631488)   // Wv^T frag-order, 2 MiB
#define WS_WOP   ((size_t)14680064)   // Wo^T frag-order, 8 MiB
#define WS_QF    ((size_t)18874368)   // Q attn-A-frag order [h][4096x128], 16 MiB
#define WS_KF    ((size_t)27262976)   // K attn-B-frag order [kvh][4096x128], 4 MiB
#define WS_VF    ((size_t)29360128)   // V attn-PV-frag order[kvh][128x4096], 4 MiB

__device__ __forceinline__ u16 f2bf(float f) {
  union { float f; u32 u; } v; v.f = f;
  u32 u = v.u;
  u += 0x7FFFu + ((u >> 16) & 1u);   // RNE
  return (u16)(u >> 16);
}

__device__ __forceinline__ void gl_lds16(const u16* g, u16* l) {
  __builtin_amdgcn_global_load_lds((const __attribute__((address_space(1))) u32*)g,
                                   (__attribute__((address_space(3))) u32*)l,
                                   16, 0, 0);
}

// fragment-order u16 offset within a 128(row) x 32(k) tile
__device__ __forceinline__ int fragoff(int row, int k) {
  return ((row >> 4) * 64 + ((k >> 3) & 3) * 16 + (row & 15)) * 8 + (k & 7);
}

// ============================================================================
// Kernel 0: one-time fp32 -> bf16 conversion into fragment-order layouts.
// ============================================================================
__global__ __launch_bounds__(256, 4)
void convert_kernel(const float* __restrict__ X,
                    const float* __restrict__ Wq,
                    const float* __restrict__ Wk,
                    const float* __restrict__ Wv,
                    const float* __restrict__ Wo,
                    u16* __restrict__ ws)
{
  const int t = blockIdx.x;
  const int tid = threadIdx.x;
  const float* src; u16* dst; int tt, ldn; bool amode = false;
  if (t < 2048)      { src = X;  dst = ws + WS_XP;  tt = t;        ldn = 2048; amode = true; }
  else if (t < 3072) { src = Wq; dst = ws + WS_WQP; tt = t - 2048; ldn = 2048; }
  else if (t < 3328) { src = Wk; dst = ws + WS_WKP; tt = t - 3072; ldn = 512;  }
  else if (t < 3584) { src = Wv; dst = ws + WS_WVP; tt = t - 3328; ldn = 512;  }
  else               { src = Wo; dst = ws + WS_WOP; tt = t - 3584; ldn = 2048; }
  const int rb = tt >> 6, kb = tt & 63;

  if (amode) {
    #pragma unroll
    for (int p = 0; p < 2; ++p) {
      const int c = tid + 256 * p;
      const int row = (c >> 6) * 16 + (c & 15);
      const int k0  = ((c >> 4) & 3) * 8;
      union { u16 h[8]; uint4 v; } pk;
      const float* s0 = src + (size_t)(rb * 128 + row) * 2048 + kb * 32 + k0;
      const float4 a0 = *reinterpret_cast<const float4*>(s0);
      const float4 a1 = *reinterpret_cast<const float4*>(s0 + 4);
      pk.h[0] = f2bf(a0.x); pk.h[1] = f2bf(a0.y); pk.h[2] = f2bf(a0.z); pk.h[3] = f2bf(a0.w);
      pk.h[4] = f2bf(a1.x); pk.h[5] = f2bf(a1.y); pk.h[6] = f2bf(a1.z); pk.h[7] = f2bf(a1.w);
      *reinterpret_cast<uint4*>(dst + (size_t)tt * 4096 + c * 8) = pk.v;
    }
  } else {
    __shared__ u16 Ls[32][136];   // [k][n], +8 pad
    #pragma unroll
    for (int i = 0; i < 4; ++i) {
      const int c = tid + 256 * i;            // 0..1023
      const int k = c >> 5, n4 = c & 31;
      const float4 wv = *reinterpret_cast<const float4*>(
          src + (size_t)(kb * 32 + k) * ldn + rb * 128 + n4 * 4);
      u16* d = &Ls[k][n4 * 4];
      d[0] = f2bf(wv.x); d[1] = f2bf(wv.y); d[2] = f2bf(wv.z); d[3] = f2bf(wv.w);
    }
    __syncthreads();
    #pragma unroll
    for (int p = 0; p < 2; ++p) {
      const int c = tid + 256 * p;
      const int row = (c >> 6) * 16 + (c & 15);
      const int k0  = ((c >> 4) & 3) * 8;
      union { u16 h[8]; uint4 v; } pk;
      #pragma unroll
      for (int j = 0; j < 8; ++j) pk.h[j] = Ls[k0 + j][row];
      *reinterpret_cast<uint4*>(dst + (size_t)tt * 4096 + c * 8) = pk.v;
    }
  }
}

// ---- shared GEMM main loop: 128x128 tile, BK=32, K=2048, frag-order inputs.
__device__ __forceinline__ void gemm_core(const u16* __restrict__ pa,
                                          const u16* __restrict__ pb,
                                          u16* As, u16* Bs,
                                          int tid, int wave, int lane,
                                          f32x4 acc[2][8])
{
  for (int it = 0; it < 64; ++it) {
    __syncthreads();
    gl_lds16(pa + tid * 8,         As + tid * 8);
    gl_lds16(pa + (tid + 256) * 8, As + (tid + 256) * 8);
    gl_lds16(pb + tid * 8,         Bs + tid * 8);
    gl_lds16(pb + (tid + 256) * 8, Bs + (tid + 256) * 8);
    pa += 4096; pb += 4096;
    __syncthreads();
    bf16x8 af0 = *reinterpret_cast<const bf16x8*>(As + (wave * 2 + 0) * 512 + lane * 8);
    bf16x8 af1 = *reinterpret_cast<const bf16x8*>(As + (wave * 2 + 1) * 512 + lane * 8);
    #pragma unroll
    for (int nt = 0; nt < 8; ++nt) {
      const bf16x8 bfr = *reinterpret_cast<const bf16x8*>(Bs + nt * 512 + lane * 8);
      acc[0][nt] = MFMA16(af0, bfr, acc[0][nt]);
      acc[1][nt] = MFMA16(af1, bfr, acc[1][nt]);
    }
  }
}

// ============================================================================
// Kernel 1: QKV GEMM + fused RoPE -> attention frag-order outputs.
// Q pre-scaled by SCALE*log2(e): attention softmax runs in exp2 domain.
// ============================================================================
__global__ __launch_bounds__(256, 3)
void qkv_kernel(const float* __restrict__ cosp,
                const float* __restrict__ sinp,
                u16* __restrict__ ws)
{
  const int mb = blockIdx.x, bn = blockIdx.y;
  const int tid = threadIdx.x;
  const int wave = tid >> 6, lane = tid & 63;
  const int lq = lane >> 4, l16 = lane & 15;

  const u16* Ab = ws + WS_XP + (size_t)mb * 64 * 4096;
  const u16* Bb; int seg, hh;
  if (bn < 16)      { Bb = ws + WS_WQP + (size_t)bn * 64 * 4096;        seg = 0; hh = bn; }
  else if (bn < 20) { Bb = ws + WS_WKP + (size_t)(bn - 16) * 64 * 4096; seg = 1; hh = bn - 16; }
  else              { Bb = ws + WS_WVP + (size_t)(bn - 20) * 64 * 4096; seg = 2; hh = bn - 20; }

  __shared__ __align__(16) u16 As[4096];
  __shared__ __align__(16) u16 Bs[4096];

  f32x4 acc[2][8];
  #pragma unroll
  for (int i = 0; i < 2; ++i)
    #pragma unroll
    for (int j = 0; j < 8; ++j)
      #pragma unroll
      for (int r = 0; r < 4; ++r) acc[i][j][r] = 0.0f;

  gemm_core(Ab, Bb, As, Bs, tid, wave, lane, acc);

  const int m0 = mb * 128;
  if (seg == 2) {          // V -> PV B-frag order (rows=d, k=t)
    u16* V = ws + WS_VF + (size_t)hh * 524288;
    #pragma unroll
    for (int mt = 0; mt < 2; ++mt)
      #pragma unroll
      for (int nt = 0; nt < 8; ++nt) {
        const int d = nt * 16 + l16;
        #pragma unroll
        for (int r = 0; r < 4; ++r) {
          const int s = m0 + wave * 32 + mt * 16 + lq * 4 + r;
          V[(s >> 5) * 4096 + fragoff(d, s & 31)] = f2bf(acc[mt][nt][r]);
        }
      }
  } else {                 // Q/K + RoPE (cos[d+64]==cos[d]); Q also *QSC
    u16* D = ws + ((seg == 0) ? WS_QF : WS_KF) + (size_t)hh * 524288;
    const float qs = (seg == 0) ? QSC : 1.0f;
    #pragma unroll
    for (int mt = 0; mt < 2; ++mt)
      #pragma unroll
      for (int r = 0; r < 4; ++r) {
        const int s = m0 + wave * 32 + mt * 16 + lq * 4 + r;
        const int sl = s & 127;
        u16* Dt = D + (size_t)(s >> 7) * 16384;
        #pragma unroll
        for (int nt = 0; nt < 4; ++nt) {
          const int d1 = nt * 16 + l16, d2 = d1 + 64;
          const float c  = cosp[s * 128 + d1];
          const float sn = sinp[s * 128 + d1];
          const float v1 = acc[mt][nt][r], v2 = acc[mt][nt + 4][r];
          Dt[(d1 >> 5) * 4096 + fragoff(sl, d1 & 31)] = f2bf((v1 * c - v2 * sn) * qs);
          Dt[(d2 >> 5) * 4096 + fragoff(sl, d2 & 31)] = f2bf((v2 * c + v1 * sn) * qs);
        }
      }
  }
}

// ============================================================================
// Kernel 2: block-sparse attention. R5 shell (2 blocks/CU, grid 512, 8 waves
// x 16 q-rows, single K/V buffer, 2 staging barriers) with:
//  - dedicated chunked P region (no bufK reuse -> 3rd barrier removed)
//  - bias table staged to LDS once (no per-iter global-latency loads)
//  - P values register-packed (2 x u16 / u32) to keep VGPR < 128
// LDS 76 KB dynamic -> 2 blocks/CU (cross-block m114 MFMA/VALU overlap).
// ============================================================================
__global__ __launch_bounds__(512, 4)
void attn_kernel(const float* __restrict__ amask, u16* __restrict__ ws)
{
  extern __shared__ __align__(16) u16 smem[];
  u16* bufK = smem;                        // 16384 u16 (32KB) K tile, B-frag
  u16* bufV = smem + 16384;                // 32KB V tile, PV B-frag
  u16* Pch  = smem + 32768;                // 8 x 512 u16 chunked P (8KB)
  float* biasL = (float*)(smem + 36864);   // 8 x 128 floats (4KB)

  const int n = 31 - blockIdx.x;           // heavy blocks first
  const int h = blockIdx.y;
  const int kvh = h >> 2;
  const int tid = threadIdx.x;
  const int wave = tid >> 6, lane = tid & 63;
  const int lq = lane >> 4, l16 = lane & 15;

  const u16* Kfb = ws + WS_KF + (size_t)kvh * 524288;
  const u16* Vfb = ws + WS_VF + (size_t)kvh * 524288;
  u16* AOp = ws + WS_AOP;
  u16* Pw = Pch + wave * 512;              // wave-private 16x32-key P chunk

  const u16* Qb = ws + WS_QF + (size_t)h * 524288 + (size_t)n * 16384;
  bf16x8 qf[4];
  #pragma unroll
  for (int kk = 0; kk < 4; ++kk)
    qf[kk] = *reinterpret_cast<const bf16x8*>(Qb + (size_t)kk * 4096 + (wave * 64 + lane) * 8);

  f32x4 O[8];
  #pragma unroll
  for (int j = 0; j < 8; ++j)
    #pragma unroll
    for (int r = 0; r < 4; ++r) O[j][r] = 0.0f;
  float mrow[4], lrow[4];
  #pragma unroll
  for (int r = 0; r < 4; ++r) { mrow[r] = -3.0e38f; lrow[r] = 0.0f; }

  // closed-form valid-kb list (reference semantics, verified R1-R6)
  const int L = (n < 3 ? n : 3) + 1;
  const int G = (n >= 25) ? 3 : (n >= 17) ? 2 : (n >= 9) ? 1 : 0;
  const int nv = L + 1 + G;
  #define KBOF(i) ((i) < L ? n - L + 1 + (i) : ((i) == L ? 0 : n - 8 * (G - ((i) - L - 1))))

  // stage bias table once: biasL[i][t] = (1-amask[KBOF(i)*128+t]) * NEGL2
  {
    const int t = tid & 127;
    #pragma unroll
    for (int p = 0; p < 2; ++p) {
      const int i = (tid >> 7) + p * 4;
      if (i < nv) {
        const int b = KBOF(i);
        biasL[i * 128 + t] = (1.0f - amask[b * 128 + t]) * NEGL2;
      }
    }
  }
  // (first loop barrier makes biasL visible before first use)

  for (int i = 0; i < nv; ++i) {
    const int bkey = KBOF(i);
    const bool intra = (i == L - 1);
    const u16* Kb = Kfb + (size_t)bkey * 16384;
    const u16* Vb = Vfb + (size_t)bkey * 16384;

    __syncthreads();                 // prior iter's K/V reads all complete
    #pragma unroll
    for (int p = 0; p < 4; ++p) {
      gl_lds16(Kb + (tid + 512 * p) * 8, bufK + (tid + 512 * p) * 8);
      gl_lds16(Vb + (tid + 512 * p) * 8, bufV + (tid + 512 * p) * 8);
    }
    __syncthreads();                 // DMA drained, tile visible

    // S = Q K^T (Q pre-scaled; scores in exp2 domain)
    f32x4 sacc[8];
    #pragma unroll
    for (int j = 0; j < 8; ++j)
      #pragma unroll
      for (int r = 0; r < 4; ++r) sacc[j][r] = 0.0f;
    #pragma unroll
    for (int kk = 0; kk < 4; ++kk)
      #pragma unroll
      for (int nt = 0; nt < 8; ++nt) {
        const bf16x8 bfr = *reinterpret_cast<const bf16x8*>(
            bufK + ((kk * 8 + nt) * 64 + lane) * 8);
        sacc[nt] = MFMA16(qf[kk], bfr, sacc[nt]);
      }

    float bias[8];
    #pragma unroll
    for (int nt = 0; nt < 8; ++nt)
      bias[nt] = biasL[i * 128 + nt * 16 + l16];

    // online softmax (exp2 domain); P values packed 2-per-u32 in registers
    u32 pbp[4][4];
    #pragma unroll
    for (int r = 0; r < 4; ++r) {
      const int tq = wave * 16 + lq * 4 + r;
      float sv[8];
      float rmax = -3.0e38f;
      #pragma unroll
      for (int nt = 0; nt < 8; ++nt) {
        float s = sacc[nt][r] + bias[nt];
        const int tk = nt * 16 + l16;
        if (intra && tk > tq) s += NEGL2;
        sv[nt] = s;
        rmax = fmaxf(rmax, s);
      }
      #pragma unroll
      for (int off = 1; off < 16; off <<= 1)
        rmax = fmaxf(rmax, __shfl_xor(rmax, off, 64));
      const float mold = mrow[r];
      const float mnew = fmaxf(mold, rmax);
      const float alpha = exp2f(mold - mnew);
      float rsum = 0.0f;
      #pragma unroll
      for (int nt = 0; nt < 8; ++nt) {
        const float pe = exp2f(sv[nt] - mnew);
        rsum += pe;
        if (nt & 1) pbp[r][nt >> 1] |= (u32)f2bf(pe) << 16;
        else        pbp[r][nt >> 1]  = (u32)f2bf(pe);
      }
      #pragma unroll
      for (int off = 1; off < 16; off <<= 1)
        rsum += __shfl_xor(rsum, off, 64);
      lrow[r] = lrow[r] * alpha + rsum;
      mrow[r] = mnew;
      #pragma unroll
      for (int nt = 0; nt < 8; ++nt) O[nt][r] *= alpha;
    }

    // O += P @ V in 32-key chunks through the wave-private P region.
    // In-wave DS ops execute in order -> write/read/overwrite is safe.
    #pragma unroll
    for (int c = 0; c < 4; ++c) {
      #pragma unroll
      for (int r = 0; r < 4; ++r) {
        const u32 pk2 = pbp[r][c];
        Pw[(((l16 >> 3)) * 16 + lq * 4 + r) * 8 + (l16 & 7)]     = (u16)pk2;
        Pw[((2 + (l16 >> 3)) * 16 + lq * 4 + r) * 8 + (l16 & 7)] = (u16)(pk2 >> 16);
      }
      const bf16x8 pf = *reinterpret_cast<const bf16x8*>(Pw + lane * 8);
      #pragma unroll
      for (int nt = 0; nt < 8; ++nt) {
        const bf16x8 vfr = *reinterpret_cast<const bf16x8*>(
            bufV + ((c * 8 + nt) * 64 + lane) * 8);
        O[nt] = MFMA16(pf, vfr, O[nt]);
      }
    }
  }
  #undef KBOF

  // finalize: write AO in outproj A-frag order
  #pragma unroll
  for (int r = 0; r < 4; ++r) {
    const float inv = 1.0f / lrow[r];
    const int s = n * 128 + wave * 16 + lq * 4 + r;
    #pragma unroll
    for (int nt = 0; nt < 8; ++nt) {
      const int kcol = h * 128 + nt * 16 + l16;
      AOp[((size_t)(s >> 7) * 64 + (kcol >> 5)) * 4096 + fragoff(s & 127, kcol & 31)] =
          f2bf(O[nt][r] * inv);
    }
  }
}

// ============================================================================
// Kernel 3: output projection. AOp fragorder @ Wop fragorder -> Out fp32.
// ============================================================================
__global__ __launch_bounds__(256, 3)
void outproj_kernel(const u16* __restrict__ ws, float* __restrict__ Out)
{
  const int mb = blockIdx.x, bn = blockIdx.y;
  const int tid = threadIdx.x;
  const int wave = tid >> 6, lane = tid & 63;
  const int lq = lane >> 4, l16 = lane & 15;

  const u16* Ab = ws + WS_AOP + (size_t)mb * 64 * 4096;
  const u16* Bb = ws + WS_WOP + (size_t)bn * 64 * 4096;

  __shared__ __align__(16) u16 As[4096];
  __shared__ __align__(16) u16 Bs[4096];

  f32x4 acc[2][8];
  #pragma unroll
  for (int i = 0; i < 2; ++i)
    #pragma unroll
    for (int j = 0; j < 8; ++j)
      #pragma unroll
      for (int r = 0; r < 4; ++r) acc[i][j][r] = 0.0f;

  gemm_core(Ab, Bb, (u16*)As, (u16*)Bs, tid, wave, lane, acc);

  #pragma unroll
  for (int mt = 0; mt < 2; ++mt)
    #pragma unroll
    for (int nt = 0; nt < 8; ++nt) {
      const int ccol = bn * 128 + nt * 16 + l16;
      #pragma unroll
      for (int r = 0; r < 4; ++r) {
        const int s = mb * 128 + wave * 32 + mt * 16 + lq * 4 + r;
        Out[(size_t)s * 2048 + ccol] = acc[mt][nt][r];
      }
    }
}

// ============================================================================
extern "C" void kernel_launch(void* const* d_in, const int* in_sizes, int n_in,
                              void* d_out, int out_size, void* d_ws, size_t ws_size,
                              hipStream_t stream) {
  const float* X     = (const float*)d_in[0];
  const float* amask = (const float*)d_in[1];
  const float* cosp  = (const float*)d_in[2];
  const float* sinp  = (const float*)d_in[3];
  const float* Wq    = (const float*)d_in[4];
  const float* Wk    = (const float*)d_in[5];
  const float* Wv    = (const float*)d_in[6];
  const float* Wo    = (const float*)d_in[7];
  float* Out = (float*)d_out;
  u16* ws = (u16*)d_ws;

  (void)hipFuncSetAttribute((const void*)attn_kernel,
                            hipFuncAttributeMaxDynamicSharedMemorySize, 77824);

  hipLaunchKernelGGL(convert_kernel, dim3(4608), dim3(256), 0, stream,
                     X, Wq, Wk, Wv, Wo, ws);
  hipLaunchKernelGGL(qkv_kernel, dim3(32, 24), dim3(256), 0, stream,
                     cosp, sinp, ws);
  hipLaunchKernelGGL(attn_kernel, dim3(32, 16), dim3(512), 77824, stream,
                     amask, ws);
  hipLaunchKernelGGL(outproj_kernel, dim3(32, 16), dim3(256), 0, stream,
                     ws, Out);
}